// Round 15
// baseline (69.968 us; speedup 1.0000x reference)
//
#include <hip/hip_runtime.h>

#define NN 2048
#define BB 4
#define IN_F 128
#define OUT_F 64

typedef __attribute__((ext_vector_type(8))) short short8;
typedef __attribute__((ext_vector_type(4))) float f32x4;
typedef __attribute__((ext_vector_type(4))) int i32x4;

__device__ __forceinline__ ushort f2bf(float f) {
  uint u = __float_as_uint(f);
  uint r = (u + 0x7fffu + ((u >> 16) & 1u)) >> 16;   // RNE, finite values
  return (ushort)r;
}
__device__ __forceinline__ float bf2f(ushort s) {
  return __uint_as_float(((uint)s) << 16);
}

// bits layout: bits2[row][m] (m = 4*t + k, m<32) is a 64-bit ballot mask;
// bit L of mask m == (adj[row*2048 + 4*(L + 64*t) + k] > 0).
// Matches the consumer's j = 4*(lane + 64*it) + k indexing exactly.

// Prep kernel, two block ranges:
//  [0,2048): bits via ballot. 1 row/wave; i32x4 loads 1KB coalesced.
//  [2048,4096): wh = h@W (4 rows/block) -> Whbf bf16 + el/er wave-reduced.
__global__ __launch_bounds__(256) void prep_kernel(
    const float* __restrict__ h, const float* __restrict__ W,
    const float* __restrict__ a, const int* __restrict__ adj,
    ushort* __restrict__ Whbf, float* __restrict__ el,
    float* __restrict__ er, uint2* __restrict__ bits2) {
  int blk = blockIdx.x;
  int lane = threadIdx.x & 63;
  if (blk < 2048) {
    int row = blk * 4 + (threadIdx.x >> 6);
    const i32x4* ar = (const i32x4*)(adj + (size_t)row * NN);
    uint2 out; out.x = 0u; out.y = 0u;
    #pragma unroll
    for (int t = 0; t < 8; ++t) {
      i32x4 v = ar[lane + 64 * t];
      unsigned long long m0 = __ballot(v.x > 0);
      unsigned long long m1 = __ballot(v.y > 0);
      unsigned long long m2 = __ballot(v.z > 0);
      unsigned long long m3 = __ballot(v.w > 0);
      if (lane == 4 * t)     { out.x = (uint)m0; out.y = (uint)(m0 >> 32); }
      if (lane == 4 * t + 1) { out.x = (uint)m1; out.y = (uint)(m1 >> 32); }
      if (lane == 4 * t + 2) { out.x = (uint)m2; out.y = (uint)(m2 >> 32); }
      if (lane == 4 * t + 3) { out.x = (uint)m3; out.y = (uint)(m3 >> 32); }
    }
    if (lane < 32) bits2[(size_t)row * 32 + lane] = out;
  } else {
    int row = (blk - 2048) * 4 + (threadIdx.x >> 6);   // b*NN + n
    int o = threadIdx.x & 63;
    const float* hr = h + (size_t)row * IN_F;
    float wh = 0.f;
    #pragma unroll 8
    for (int f = 0; f < IN_F; ++f) wh += hr[f] * W[f * OUT_F + o];
    Whbf[(size_t)row * OUT_F + o] = f2bf(wh);
    float vl = wh * a[o];
    float vr = wh * a[OUT_F + o];
    #pragma unroll
    for (int d = 32; d > 0; d >>= 1) {
      vl += __shfl_down(vl, d);
      vr += __shfl_down(vr, d);
    }
    if (o == 0) { el[row] = vl; er[row] = vr; }
  }
}

// Kernel 1b: WhbfT[b][o][j] = Whbf[b][j][o] (bf16 transpose, 64x2048/batch).
__global__ __launch_bounds__(256) void transpose_kernel(
    const ushort* __restrict__ Whbf, ushort* __restrict__ WhbfT) {
  __shared__ uint tile[64][65];
  int b = blockIdx.x >> 5;
  int j0 = (blockIdx.x & 31) << 6;
  int t = threadIdx.x;
  int o = t & 63, jg = t >> 6;
  #pragma unroll
  for (int m = 0; m < 16; ++m) {
    int jj = jg * 16 + m;
    tile[jj][o] = (uint)Whbf[((size_t)(b * NN + j0 + jj)) * OUT_F + o];
  }
  __syncthreads();
  int oo = t >> 2, grp = t & 3;
  uint out[8];
  #pragma unroll
  for (int m = 0; m < 16; m += 2) {
    uint u0 = tile[grp * 16 + m][oo];
    uint u1 = tile[grp * 16 + m + 1][oo];
    out[m >> 1] = u0 | (u1 << 16);
  }
  uint4* dst = (uint4*)(WhbfT + ((size_t)(b * OUT_F + oo)) * NN + j0 + grp * 16);
  dst[0] = *(uint4*)&out[0];
  dst[1] = *(uint4*)&out[4];
}

// MFMA kernel: block = 16 rows, 512 threads (8 waves), 2 rows/wave.
// Phase 1: exp from bits (L2) -> unnormalized bf16 p -> swizzled pbuf + sinv.
// Bit extraction: select own half LOCALLY (convergent), then ONE full-exec
// shfl with per-lane src index (src lanes always active -> defined).
// Phase 2 (all 8 waves): MFMA p @ Wh (o-tile x k-half), LDS reduce -> hprime.
__global__ __launch_bounds__(512, 4) void mfma_kernel(
    const uint2* __restrict__ bits2, const ushort* __restrict__ WhbfT,
    const float* __restrict__ el, const float* __restrict__ er,
    float* __restrict__ hprime) {
  __shared__ __align__(16) char pbuf[16 * 4096];  // 64 KB: p bf16 [16][2048]
  __shared__ float ers[NN];                       // 8 KB
  __shared__ float red[4][16][17];                // 4.4 KB cross-khalf reduce
  __shared__ float sinv[16];

  int blk = blockIdx.x;
  int b = blk >> 7;
  int i0 = (blk & 127) << 4;
  int tid = threadIdx.x;
  int wave = tid >> 6, lane = tid & 63;

  ((f32x4*)ers)[tid] = ((const f32x4*)(er + (size_t)b * NN))[tid];
  __syncthreads();

  int r0 = wave * 2, r1 = r0 + 1;
  int ia = i0 + r0, ib = i0 + r1;
  float el0 = el[(size_t)b * NN + ia];
  float el1 = el[(size_t)b * NN + ib];
  uint2 mw0 = bits2[(size_t)(b * NN + ia) * 32 + (lane & 31)];
  uint2 mw1 = bits2[(size_t)(b * NN + ib) * 32 + (lane & 31)];
  // lane<32 holds .x of mask (lane); lane>=32 holds .y of mask (lane-32)
  uint wsel0 = lane < 32 ? mw0.x : mw0.y;
  uint wsel1 = lane < 32 ? mw1.x : mw1.y;
  int shalf = lane & 32;
  int bitpos = lane & 31;

  uint2 pva0[8], pva1[8];
  float ss0 = 0.f, ss1 = 0.f;
  #pragma unroll
  for (int it = 0; it < 8; ++it) {
    f32x4 ev = *(const f32x4*)&ers[(lane + 64 * it) * 4];
    float evv[4] = {ev.x, ev.y, ev.z, ev.w};
    float pe0[4], pe1[4];
    #pragma unroll
    for (int k = 0; k < 4; ++k) {
      uint s0 = __shfl(wsel0, 4 * it + k + shalf);   // full-exec, src active
      uint s1 = __shfl(wsel1, 4 * it + k + shalf);
      float e0 = el0 + evv[k];
      e0 = fmaxf(e0, 0.2f * e0);            // leaky_relu 0.2
      float x0 = __expf(e0);                // |e| <~ 12, f32-safe unnormalized
      pe0[k] = (s0 >> bitpos) & 1 ? x0 : 0.f;
      ss0 += pe0[k];
      float e1 = el1 + evv[k];
      e1 = fmaxf(e1, 0.2f * e1);
      float x1 = __expf(e1);
      pe1[k] = (s1 >> bitpos) & 1 ? x1 : 0.f;
      ss1 += pe1[k];
    }
    uint2 w0, w1;
    w0.x = (uint)f2bf(pe0[0]) | ((uint)f2bf(pe0[1]) << 16);
    w0.y = (uint)f2bf(pe0[2]) | ((uint)f2bf(pe0[3]) << 16);
    w1.x = (uint)f2bf(pe1[0]) | ((uint)f2bf(pe1[1]) << 16);
    w1.y = (uint)f2bf(pe1[2]) | ((uint)f2bf(pe1[3]) << 16);
    pva0[it] = w0;
    pva1[it] = w1;
  }
  #pragma unroll
  for (int d = 32; d > 0; d >>= 1) {
    ss0 += __shfl_xor(ss0, d);
    ss1 += __shfl_xor(ss1, d);
  }
  if (lane == 0) { sinv[r0] = 1.f / ss0; sinv[r1] = 1.f / ss1; }

  {
    char* lr0 = pbuf + r0 * 4096;
    char* lr1 = pbuf + r1 * 4096;
    int sw0 = (r0 & 7) << 4, sw1 = (r1 & 7) << 4;
    #pragma unroll
    for (int it = 0; it < 8; ++it) {
      *(uint2*)(lr0 + (((lane + 64 * it) * 8) ^ sw0)) = pva0[it];
      *(uint2*)(lr1 + (((lane + 64 * it) * 8) ^ sw1)) = pva1[it];
    }
  }
  __syncthreads();

  // ---- Phase 2: MFMA p @ Wh; wave = (ntile = w>>1, khalf = w&1) ----
  int ntile = wave >> 1, khalf = wave & 1;
  int o0 = ntile * 16;
  int lo16 = lane & 15, hi4 = lane >> 4;

  const char* prowA = pbuf + lo16 * 4096;
  int swA = (lo16 & 7) << 4;
  const ushort* brow = WhbfT + ((size_t)(b * OUT_F + o0 + lo16)) * NN;

  f32x4 acc = {0.f, 0.f, 0.f, 0.f};
  #pragma unroll 8
  for (int kk = 0; kk < 32; ++kk) {
    int kbase = khalf * 1024 + kk * 32 + hi4 * 8;
    short8 afrag = *(const short8*)(prowA + ((kbase * 2) ^ swA));
    short8 bfrag = *(const short8*)(brow + kbase);
    acc = __builtin_amdgcn_mfma_f32_16x16x32_bf16(afrag, bfrag, acc, 0, 0, 0);
  }

  if (khalf == 1) {
    #pragma unroll
    for (int q = 0; q < 4; ++q) red[ntile][hi4 * 4 + q][lo16] = acc[q];
  }
  __syncthreads();
  if (khalf == 0) {
    #pragma unroll
    for (int q = 0; q < 4; ++q) {
      int crow = hi4 * 4 + q;
      float v = (acc[q] + red[ntile][crow][lo16]) * sinv[crow];
      v = v > 0.f ? v : 0.01f * v;           // leaky_relu 0.01
      hprime[((size_t)(b * NN + i0 + crow)) * OUT_F + o0 + lo16] = v;
    }
  }
}

// Store kernel: PURE attention write stream. 1 row/wave, 4 waves/block,
// 2048 blocks, no LDS, no barriers. Recomputes exp from bits (L2) + er (L2),
// shfl row-sum, streams 67 MB of normalized f32 attention.
__global__ __launch_bounds__(256) void store_kernel(
    const uint2* __restrict__ bits2, const float* __restrict__ el,
    const float* __restrict__ er, float* __restrict__ attn_out) {
  int lane = threadIdx.x & 63;
  int row = blockIdx.x * 4 + (threadIdx.x >> 6);   // b*NN + i
  int b = row >> 11;
  float eli = el[row];
  const f32x4* er4 = (const f32x4*)(er + ((size_t)b << 11));
  uint2 mw = bits2[(size_t)row * 32 + (lane & 31)];
  uint wsel = lane < 32 ? mw.x : mw.y;
  int shalf = lane & 32;
  int bitpos = lane & 31;

  float pv[8][4];
  float ss = 0.f;
  #pragma unroll
  for (int it = 0; it < 8; ++it) {
    f32x4 ev = er4[lane + 64 * it];
    float evv[4] = {ev.x, ev.y, ev.z, ev.w};
    #pragma unroll
    for (int k = 0; k < 4; ++k) {
      uint s = __shfl(wsel, 4 * it + k + shalf);     // full-exec, src active
      float e = eli + evv[k];
      e = fmaxf(e, 0.2f * e);                // leaky_relu 0.2
      float x = __expf(e);
      float pe = (s >> bitpos) & 1 ? x : 0.f;
      pv[it][k] = pe;
      ss += pe;
    }
  }
  #pragma unroll
  for (int d = 32; d > 0; d >>= 1) ss += __shfl_xor(ss, d);
  float inv = 1.f / ss;

  f32x4* orow = (f32x4*)(attn_out + (size_t)row * NN);
  #pragma unroll
  for (int it = 0; it < 8; ++it) {
    f32x4 v;
    v.x = pv[it][0] * inv;
    v.y = pv[it][1] * inv;
    v.z = pv[it][2] * inv;
    v.w = pv[it][3] * inv;
    orow[lane + 64 * it] = v;
  }
}

extern "C" void kernel_launch(void* const* d_in, const int* in_sizes, int n_in,
                              void* d_out, int out_size, void* d_ws, size_t ws_size,
                              hipStream_t stream) {
  const float* h  = (const float*)d_in[0];
  const int* adj  = (const int*)d_in[1];
  const float* W  = (const float*)d_in[2];
  const float* a  = (const float*)d_in[3];

  float* hprime   = (float*)d_out;                           // B*N*OUT_F
  float* attn_out = (float*)d_out + (size_t)BB * NN * OUT_F; // B*N*N

  // workspace: Whbf (1MB), WhbfT (1MB), el/er (64KB), bits2 (2MB)
  ushort* Whbf  = (ushort*)d_ws;
  ushort* WhbfT = Whbf + (size_t)BB * NN * OUT_F;
  float* el = (float*)(WhbfT + (size_t)BB * OUT_F * NN);
  float* er = el + (size_t)BB * NN;
  uint2* bits2 = (uint2*)(er + (size_t)BB * NN);

  hipLaunchKernelGGL(prep_kernel, dim3(4096), dim3(256), 0, stream,
                     h, W, a, adj, Whbf, el, er, bits2);
  hipLaunchKernelGGL(transpose_kernel, dim3(BB * (NN / 64)), dim3(256), 0, stream,
                     Whbf, WhbfT);
  hipLaunchKernelGGL(mfma_kernel, dim3(BB * (NN / 16)), dim3(512), 0, stream,
                     bits2, WhbfT, el, er, hprime);
  hipLaunchKernelGGL(store_kernel, dim3(BB * NN / 4), dim3(256), 0, stream,
                     bits2, el, er, attn_out);
}